// Round 1
// baseline (1492.696 us; speedup 1.0000x reference)
//
#include <hip/hip_runtime.h>
#include <math.h>

// ---------------------------------------------------------------------------
// Batched Levenberg-Marquardt, Huber IRLS, B=32, M=307200, N=4, 30 steps.
//
// Fusion: cost(theta_k) and H,G(theta_k) computed in ONE pass (the reference
// always accepts the step, so the cost-eval point of step k == the H/G point
// of step k+1).  31 data passes total instead of 61.
//
// ws layout (floats):
//   [0,128)        theta       (32 x 4)  committed theta
//   [128,256)      eval_theta  (32 x 4)  point the current pass evaluates
//   [256,288)      lambda      (32)
//   [288,320)      cost        (32)
//   [320,352)      stop flags  (32, as int)
//   [352,352+16384) partials   (32 batches x 32 blocks x 16 floats)
// total 16736 floats = 66,944 bytes.
// ---------------------------------------------------------------------------

#define B_   32
#define M_   307200
#define NSTEPS 30
#define BLK_PER_BATCH 32
#define THREADS 256
#define STRIDE (BLK_PER_BATCH * THREADS)   // 8192

#define WS_THETA 0
#define WS_EVAL  128
#define WS_LAMB  256
#define WS_COST  288
#define WS_STOP  320
#define WS_PART  352

__global__ void lm_init(float* __restrict__ ws, const float* __restrict__ theta0) {
    int i = threadIdx.x;
    if (i < 128) {
        float t = theta0[i];
        ws[WS_THETA + i] = t;
        ws[WS_EVAL + i]  = t;
    }
    if (i < 32) {
        ws[WS_LAMB + i] = 0.1f;
        ws[WS_COST + i] = 0.0f;
        ((int*)(ws + WS_STOP))[i] = 0;
    }
}

// One fused data pass: residual -> huber weight -> accumulate {cost, G(4), H(10)}
// per batch.  Deterministic: shuffle-reduce per wave, LDS across waves, one
// 15-float partial per block; cross-block sum done in lm_solve.
__global__ __launch_bounds__(THREADS) void lm_pass(
        const float* __restrict__ J, const float* __restrict__ bvec,
        const float* __restrict__ conf, float* __restrict__ ws) {
    const int batch = blockIdx.x & (BLK_PER_BATCH - 1);
    const int chunk = blockIdx.x >> 5;

    const int* stopf = (const int*)(ws + WS_STOP);
    if (stopf[batch]) return;   // frozen batch: results would be discarded

    const float* th = ws + WS_EVAL + batch * 4;
    const float t0 = th[0], t1 = th[1], t2 = th[2], t3 = th[3];

    const float4* Jb = (const float4*)(J + (size_t)batch * M_ * 4);
    const float*  bb = bvec + (size_t)batch * M_;
    const float*  cb = conf + (size_t)batch * M_;

    float c_acc = 0.f;
    float g0 = 0.f, g1 = 0.f, g2 = 0.f, g3 = 0.f;
    float h00 = 0.f, h01 = 0.f, h02 = 0.f, h03 = 0.f;
    float h11 = 0.f, h12 = 0.f, h13 = 0.f;
    float h22 = 0.f, h23 = 0.f, h33 = 0.f;

    for (int m = chunk * THREADS + (int)threadIdx.x; m < M_; m += STRIDE) {
        float4 jv = Jb[m];
        float  bv = bb[m];
        float  cf = cb[m];
        float pred = jv.x * t0 + jv.y * t1 + jv.z * t2 + jv.w * t3;
        float r = bv - pred;
        // scaled huber, a = 0.01 -> a^2 = 1e-4, x = r^2 / a^2
        float x  = r * r * 1.0e4f;
        float sx = sqrtf(x + 1e-8f);
        float isx = fmaxf(1.1920929e-7f, 1.0f / sx);
        bool small = (x <= 1.0f);
        float loss = small ? x : (2.0f * sx - 1.0f);
        float d1   = small ? 1.0f : isx;
        c_acc += loss * 1.0e-4f * cf;
        float w  = d1 * cf;
        float wr = w * r;
        g0 += wr * jv.x; g1 += wr * jv.y; g2 += wr * jv.z; g3 += wr * jv.w;
        float wx = w * jv.x, wy = w * jv.y, wz = w * jv.z;
        h00 += wx * jv.x; h01 += wx * jv.y; h02 += wx * jv.z; h03 += wx * jv.w;
        h11 += wy * jv.y; h12 += wy * jv.z; h13 += wy * jv.w;
        h22 += wz * jv.z; h23 += wz * jv.w;
        h33 += (w * jv.w) * jv.w;
    }

    float acc[15] = {c_acc, g0, g1, g2, g3,
                     h00, h01, h02, h03, h11, h12, h13, h22, h23, h33};
    #pragma unroll
    for (int v = 0; v < 15; ++v) {
        float s = acc[v];
        #pragma unroll
        for (int off = 32; off > 0; off >>= 1)
            s += __shfl_down(s, off, 64);
        acc[v] = s;
    }

    __shared__ float red[4][15];
    const int lane = threadIdx.x & 63;
    const int wave = threadIdx.x >> 6;
    if (lane == 0) {
        #pragma unroll
        for (int v = 0; v < 15; ++v) red[wave][v] = acc[v];
    }
    __syncthreads();
    if (threadIdx.x < 15) {
        int v = threadIdx.x;
        float s = red[0][v] + red[1][v] + red[2][v] + red[3][v];
        ws[WS_PART + (batch * BLK_PER_BATCH + chunk) * 16 + v] = s;
    }
}

// Cross-block reduce + state update + damped 4x4 Cholesky solve.
// j==0: produce cost0 and the first candidate step.
// j>=1: commit new_theta/new_cost, lambda update, early-stop, next candidate.
// j==NSTEPS: final commit + write outputs.
__global__ __launch_bounds__(64) void lm_solve(
        float* __restrict__ ws, float* __restrict__ out, int j) {
    const int batch = blockIdx.x;
    const int tid = threadIdx.x;
    float* theta = ws + WS_THETA + batch * 4;
    float* evalt = ws + WS_EVAL + batch * 4;
    float* lambp = ws + WS_LAMB + batch;
    float* costp = ws + WS_COST + batch;
    int*   stopp = (int*)(ws + WS_STOP) + batch;
    const float* part = ws + WS_PART + batch * BLK_PER_BATCH * 16;

    __shared__ float vals[15];
    const bool stopped = (*stopp != 0);   // block-uniform

    if (!stopped) {
        if (tid < 15) {
            float s = 0.f;
            #pragma unroll 4
            for (int k = 0; k < BLK_PER_BATCH; ++k) s += part[k * 16 + tid];
            vals[tid] = s;
        }
        __syncthreads();
        if (tid == 0) {
            float new_cost = vals[0];
            float l = *lambp;
            bool stop_now = false;
            if (j == 0) {
                *costp = new_cost;           // cost0; theta/eval already theta0
            } else {
                float prev = *costp;
                float nl = l * (new_cost > prev ? 10.0f : 0.1f);
                nl = fminf(fmaxf(nl, 1e-6f), 100.0f);
                stop_now = fabsf(new_cost - prev) <= (1e-8f + 1e-8f * fabsf(prev));
                theta[0] = evalt[0]; theta[1] = evalt[1];
                theta[2] = evalt[2]; theta[3] = evalt[3];
                *costp = new_cost;
                *lambp = nl;
                l = nl;
                if (stop_now) *stopp = 1;
            }
            if (!stop_now && j < NSTEPS) {
                float g0 = vals[1], g1 = vals[2], g2 = vals[3], g3 = vals[4];
                float a00 = vals[5],  a01 = vals[6],  a02 = vals[7], a03 = vals[8];
                float a11 = vals[9],  a12 = vals[10], a13 = vals[11];
                float a22 = vals[12], a23 = vals[13], a33 = vals[14];
                // LM damping: H[i][i] += max(lambda * H[i][i], 1e-6)
                a00 += fmaxf(l * a00, 1e-6f);
                a11 += fmaxf(l * a11, 1e-6f);
                a22 += fmaxf(l * a22, 1e-6f);
                a33 += fmaxf(l * a33, 1e-6f);
                // Cholesky
                float L00 = sqrtf(a00);
                float L10 = a01 / L00, L20 = a02 / L00, L30 = a03 / L00;
                float L11 = sqrtf(a11 - L10 * L10);
                float L21 = (a12 - L20 * L10) / L11;
                float L31 = (a13 - L30 * L10) / L11;
                float L22 = sqrtf(a22 - L20 * L20 - L21 * L21);
                float L32 = (a23 - L30 * L20 - L31 * L21) / L22;
                float L33 = sqrtf(a33 - L30 * L30 - L31 * L31 - L32 * L32);
                // forward solve L y = G
                float y0 = g0 / L00;
                float y1 = (g1 - L10 * y0) / L11;
                float y2 = (g2 - L20 * y0 - L21 * y1) / L22;
                float y3 = (g3 - L30 * y0 - L31 * y1 - L32 * y2) / L33;
                // back solve L^T d = y
                float d3 = y3 / L33;
                float d2 = (y2 - L32 * d3) / L22;
                float d1 = (y1 - L21 * d2 - L31 * d3) / L11;
                float d0 = (y0 - L10 * d1 - L20 * d2 - L30 * d3) / L00;
                evalt[0] = theta[0] + d0;
                evalt[1] = theta[1] + d1;
                evalt[2] = theta[2] + d2;
                evalt[3] = theta[3] + d3;
            }
        }
    }

    if (j == NSTEPS) {
        __syncthreads();
        if (tid < 4)       out[batch * 4 + tid] = theta[tid];
        else if (tid == 4) out[B_ * 4 + batch]  = *costp;
    }
}

extern "C" void kernel_launch(void* const* d_in, const int* in_sizes, int n_in,
                              void* d_out, int out_size, void* d_ws, size_t ws_size,
                              hipStream_t stream) {
    const float* J      = (const float*)d_in[0];
    const float* bvec   = (const float*)d_in[1];
    const float* conf   = (const float*)d_in[2];
    const float* theta0 = (const float*)d_in[3];
    float* ws  = (float*)d_ws;
    float* out = (float*)d_out;

    hipLaunchKernelGGL(lm_init, dim3(1), dim3(128), 0, stream, ws, theta0);
    for (int j = 0; j <= NSTEPS; ++j) {
        hipLaunchKernelGGL(lm_pass, dim3(B_ * BLK_PER_BATCH), dim3(THREADS), 0, stream,
                           J, bvec, conf, ws);
        hipLaunchKernelGGL(lm_solve, dim3(B_), dim3(64), 0, stream, ws, out, j);
    }
}